// Round 4
// baseline (318.036 us; speedup 1.0000x reference)
//
#include <hip/hip_runtime.h>
#include <hip/hip_bf16.h>
#include <math.h>

// Problem constants (fixed by setup_inputs)
constexpr int B    = 4;
constexpr int N    = 8192;
constexpr int COUT = 64;
constexpr int E    = B * N * 32;      // 1048576 edges
constexpr int PERB = N * 32;          // 262144 elements per (b,o) norm group
constexpr int TILES  = E / 16;        // 65536 16-edge tiles
constexpr int TPW    = 8;             // tiles per wave
constexpr int TPB    = TPW * 4;       // 32 tiles per block
constexpr int BLOCKS = TILES / TPB;   // 2048 (512 per batch)
constexpr float EPS   = 1e-5f;
constexpr float SLOPE = 0.1f;

// Tiled-pack activation layout (bf16):
//   addr(c, e) = (e>>4)*1024 + (c>>3)*128 + (e&15)*8 + (c&7)    [ushort units]
// -> MFMA B-frag (8 ch of one edge) = one 16B load; C-store = 8B per m-tile.

typedef __attribute__((ext_vector_type(8))) short short8;
typedef __attribute__((ext_vector_type(4))) float f32x4;
#define MFMA16 __builtin_amdgcn_mfma_f32_16x16x32_bf16

union S8 { short8 s; unsigned int u[4]; };

__device__ __forceinline__ float bflo(unsigned int u) {
    union { unsigned int x; float f; } v; v.x = u << 16; return v.f;
}
__device__ __forceinline__ float bfhi(unsigned int u) {
    union { unsigned int x; float f; } v; v.x = u & 0xFFFF0000u; return v.f;
}
// packed f32x2 -> bf16x2 (RTNE); low 16 bits = a
__device__ __forceinline__ unsigned int pk2(float a, float b) {
    union { __hip_bfloat162 h; unsigned int u; } v;
    v.h = __float22bfloat162_rn(make_float2(a, b));
    return v.u;
}
__device__ __forceinline__ float lrelu(float z) {
    return fmaxf(z, SLOPE * z);
}
__device__ __forceinline__ short8 pack8(const float* f) {
    S8 r;
#pragma unroll
    for (int i = 0; i < 4; ++i) r.u[i] = pk2(f[2 * i], f[2 * i + 1]);
    return r.s;
}
// unpack 8 bf16, apply per-channel scale/shift + leaky relu, repack bf16
__device__ __forceinline__ short8 xform(uint4 raw, const float* sc, const float* sh) {
    unsigned int w[4] = {raw.x, raw.y, raw.z, raw.w};
    S8 r;
#pragma unroll
    for (int i = 0; i < 4; ++i) {
        float z0 = fmaf(bflo(w[i]), sc[2 * i],     sh[2 * i]);
        float z1 = fmaf(bfhi(w[i]), sc[2 * i + 1], sh[2 * i + 1]);
        r.u[i] = pk2(lrelu(z0), lrelu(z1));
    }
    return r.s;
}

// ---------------------------------------------------------------------------
__global__ void detect_i32(const unsigned int* __restrict__ w, int* __restrict__ flag) {
    unsigned long long m = __ballot(w[2 * threadIdx.x + 1] != 0u);
    if (threadIdx.x == 0) *flag = (m != 0ull) ? 1 : 0;
}

// ---------------------------------------------------------------------------
// Shared epilogue: per-(b,o) sum/sumsq partials -> partials[ablk][o*2+{0,1}]
__device__ __forceinline__ void stats_epilogue(
        float (&sacc)[4][4], float (&s2acc)[4][4],
        int tid, int wv, int col, int quad, int ablk,
        float* __restrict__ partials) {
    __shared__ float lds[2][4][64];
#pragma unroll
    for (int m = 0; m < 4; ++m)
#pragma unroll
        for (int r = 0; r < 4; ++r) {
            float s = sacc[m][r], s2 = s2acc[m][r];
#pragma unroll
            for (int d = 1; d < 16; d <<= 1) {
                s  += __shfl_xor(s,  d, 16);
                s2 += __shfl_xor(s2, d, 16);
            }
            if (col == 0) {
                int o = m * 16 + quad * 4 + r;
                lds[0][wv][o] = s;
                lds[1][wv][o] = s2;
            }
        }
    __syncthreads();
    if (tid < 64) {
        float s  = lds[0][0][tid] + lds[0][1][tid] + lds[0][2][tid] + lds[0][3][tid];
        float s2 = lds[1][0][tid] + lds[1][1][tid] + lds[1][2][tid] + lds[1][3][tid];
        ((float2*)(partials + (size_t)ablk * 128))[tid] = make_float2(s, s2);
    }
}

// ---------------------------------------------------------------------------
// Layer 1: gather + concat + MFMA (K=35 padded to 64). Writes TP layout + stats.
__global__ __launch_bounds__(256) void mfma_stage1(
        const float* __restrict__ signal,   // (BN, 32)
        const void*  __restrict__ edges,
        const float* __restrict__ ef,       // (E, 3)
        const float* __restrict__ W1,       // (64, 35)
        unsigned short* __restrict__ Y,
        const int* __restrict__ flag,
        float* __restrict__ partials) {
    const int tid = threadIdx.x, lane = tid & 63, wv = tid >> 6;
    const int col = lane & 15, quad = lane >> 4;

    short8 afrag[4][2];
#pragma unroll
    for (int m = 0; m < 4; ++m) {
        const float* wr = W1 + (m * 16 + col) * 35;
        float f[8];
#pragma unroll
        for (int j = 0; j < 8; ++j) f[j] = wr[quad * 8 + j];
        afrag[m][0] = pack8(f);
#pragma unroll
        for (int j = 0; j < 8; ++j) f[j] = (quad == 0 && j < 3) ? wr[32 + j] : 0.f;
        afrag[m][1] = pack8(f);
    }
    const bool is32 = (*flag != 0);
    const int* ip = (const int*)edges;
    const long long* lp = (const long long*)edges;

    float sacc[4][4] = {{0.f}}, s2acc[4][4] = {{0.f}};
    const int tile0 = blockIdx.x * TPB + wv * TPW;

    for (int ti = 0; ti < TPW; ++ti) {
        const int tile = tile0 + ti;
        const int e = tile * 16 + col;
        long long idx = is32 ? (long long)ip[e] : lp[e];
        const float4* s4 = (const float4*)(signal + idx * 32 + quad * 8);
        float4 v0 = s4[0], v1 = s4[1];
        float f[8] = {v0.x, v0.y, v0.z, v0.w, v1.x, v1.y, v1.z, v1.w};
        short8 b0 = pack8(f);
        float g[8] = {0.f, 0.f, 0.f, 0.f, 0.f, 0.f, 0.f, 0.f};
        if (quad == 0) { g[0] = ef[e * 3]; g[1] = ef[e * 3 + 1]; g[2] = ef[e * 3 + 2]; }
        short8 b1 = pack8(g);

        unsigned short* tp = Y + (size_t)tile * 1024;
#pragma unroll
        for (int m = 0; m < 4; ++m) {
            f32x4 acc = {0.f, 0.f, 0.f, 0.f};
            acc = MFMA16(afrag[m][0], b0, acc, 0, 0, 0);
            acc = MFMA16(afrag[m][1], b1, acc, 0, 0, 0);
            *(uint2*)(tp + (m * 2 + (quad >> 1)) * 128 + col * 8 + (quad & 1) * 4) =
                make_uint2(pk2(acc[0], acc[1]), pk2(acc[2], acc[3]));
#pragma unroll
            for (int r = 0; r < 4; ++r) {
                float v = acc[r];
                sacc[m][r] += v;
                s2acc[m][r] = fmaf(v, v, s2acc[m][r]);
            }
        }
    }
    stats_epilogue(sacc, s2acc, tid, wv, col, quad, blockIdx.x, partials);
}

// ---------------------------------------------------------------------------
// Layers 2/3: in-place TP GEMM: Y[o] = W * lrelu(scale*Y + shift), + stats.
// dir=1 walks blocks in reverse so we read the previous stage's most-recent
// writes first (LLC serpentine). partials indexed by logical block (ablk).
__global__ __launch_bounds__(256) void mfma_stage(
        unsigned short* __restrict__ Y,         // in-place (per-tile wave-exclusive)
        const float* __restrict__ W,            // (64, 64)
        const float* __restrict__ scale,        // (B, 64)
        const float* __restrict__ shift,
        float* __restrict__ partials,
        const int dir) {
    const int tid = threadIdx.x, lane = tid & 63, wv = tid >> 6;
    const int col = lane & 15, quad = lane >> 4;
    const int ablk = dir ? (BLOCKS - 1 - blockIdx.x) : blockIdx.x;
    const int b    = ablk >> 9;                 // 512 blocks per batch

    short8 afrag[4][2];
#pragma unroll
    for (int m = 0; m < 4; ++m)
#pragma unroll
        for (int kc = 0; kc < 2; ++kc) {
            const float4* wp = (const float4*)(W + (m * 16 + col) * 64 + kc * 32 + quad * 8);
            float4 w0 = wp[0], w1 = wp[1];
            float f[8] = {w0.x, w0.y, w0.z, w0.w, w1.x, w1.y, w1.z, w1.w};
            afrag[m][kc] = pack8(f);
        }
    float sc[2][8], sh[2][8];
#pragma unroll
    for (int kc = 0; kc < 2; ++kc) {
        const int c0 = (kc * 4 + quad) * 8;
#pragma unroll
        for (int j = 0; j < 8; ++j) {
            sc[kc][j] = scale[b * COUT + c0 + j];
            sh[kc][j] = shift[b * COUT + c0 + j];
        }
    }
    float sacc[4][4] = {{0.f}}, s2acc[4][4] = {{0.f}};
    const int tile0 = ablk * TPB + wv * TPW;

    for (int ti = 0; ti < TPW; ++ti) {
        unsigned short* tp = Y + (size_t)(tile0 + ti) * 1024;
        uint4 r0 = *(const uint4*)(tp + quad * 128 + col * 8);
        uint4 r1 = *(const uint4*)(tp + 512 + quad * 128 + col * 8);
        short8 b0 = xform(r0, sc[0], sh[0]);
        short8 b1 = xform(r1, sc[1], sh[1]);
#pragma unroll
        for (int m = 0; m < 4; ++m) {
            f32x4 acc = {0.f, 0.f, 0.f, 0.f};
            acc = MFMA16(afrag[m][0], b0, acc, 0, 0, 0);
            acc = MFMA16(afrag[m][1], b1, acc, 0, 0, 0);
            *(uint2*)(tp + (m * 2 + (quad >> 1)) * 128 + col * 8 + (quad & 1) * 4) =
                make_uint2(pk2(acc[0], acc[1]), pk2(acc[2], acc[3]));
#pragma unroll
            for (int r = 0; r < 4; ++r) {
                float v = acc[r];
                sacc[m][r] += v;
                s2acc[m][r] = fmaf(v, v, s2acc[m][r]);
            }
        }
    }
    stats_epilogue(sacc, s2acc, tid, wv, col, quad, ablk, partials);
}

// ---------------------------------------------------------------------------
// Parallel finalize: one block per (o,b); 256 threads sum that batch's partials.
__global__ __launch_bounds__(256) void finalize_k(
        const float* __restrict__ partials,
        const float* __restrict__ gamma,
        const float* __restrict__ beta,
        float* __restrict__ scale,
        float* __restrict__ shift) {
    const int g = blockIdx.x;        // 0..255
    const int o = g >> 2, b = g & 3;
    const int k = threadIdx.x;       // 0..255
    float s = 0.f, s2 = 0.f;
    for (int j = k; j < 512; j += 256) {
        const float* p = partials + (size_t)(b * 512 + j) * 128 + o * 2;
        s += p[0]; s2 += p[1];
    }
    __shared__ float red[512];
    red[k] = s; red[256 + k] = s2;
    __syncthreads();
    for (int st = 128; st > 0; st >>= 1) {
        if (k < st) { red[k] += red[k + st]; red[256 + k] += red[256 + k + st]; }
        __syncthreads();
    }
    if (k == 0) {
        const float inv_n = 1.f / (float)PERB;
        float mean = red[0] * inv_n;
        float var  = red[256] * inv_n - mean * mean;
        float inv  = rsqrtf(var + EPS);
        float scv  = gamma[o] * inv;
        scale[b * COUT + o] = scv;
        shift[b * COUT + o] = beta[o] - mean * scv;
    }
}

// ---------------------------------------------------------------------------
// Pool: max over K=32 edges (2 TP tiles) per (bn, channel-group), then affine
// + single lrelu (monotone). Reverse block order (stage3 wrote ascending).
__global__ __launch_bounds__(256) void pool_k(
        const unsigned short* __restrict__ Y,
        const float* __restrict__ scale,
        const float* __restrict__ shift,
        float* __restrict__ out) {
    const int t  = (gridDim.x - 1 - blockIdx.x) * 256 + threadIdx.x;  // 0..262143
    const int og = t & 7;
    const int bn = t >> 3;
    const int b  = bn >> 13;
    float mx[8], mn[8];
#pragma unroll
    for (int j = 0; j < 8; ++j) { mx[j] = -1e30f; mn[j] = 1e30f; }
#pragma unroll
    for (int half = 0; half < 2; ++half) {
        const unsigned short* p = Y + (size_t)(bn * 2 + half) * 1024 + og * 128;
#pragma unroll
        for (int e = 0; e < 16; ++e) {
            uint4 v = *(const uint4*)(p + e * 8);
            unsigned int w[4] = {v.x, v.y, v.z, v.w};
#pragma unroll
            for (int i = 0; i < 4; ++i) {
                float f0 = bflo(w[i]), f1 = bfhi(w[i]);
                mx[2 * i]     = fmaxf(mx[2 * i], f0);
                mn[2 * i]     = fminf(mn[2 * i], f0);
                mx[2 * i + 1] = fmaxf(mx[2 * i + 1], f1);
                mn[2 * i + 1] = fminf(mn[2 * i + 1], f1);
            }
        }
    }
    float r[8];
#pragma unroll
    for (int j = 0; j < 8; ++j) {
        const int o = og * 8 + j;
        const float s = scale[b * COUT + o], h = shift[b * COUT + o];
        float m = (s >= 0.f ? mx[j] : mn[j]) * s + h;
        r[j] = lrelu(m);
    }
    float4* q = (float4*)(out + (size_t)bn * COUT + og * 8);
    q[0] = make_float4(r[0], r[1], r[2], r[3]);
    q[1] = make_float4(r[4], r[5], r[6], r[7]);
}

// ---------------------------------------------------------------------------
extern "C" void kernel_launch(void* const* d_in, const int* in_sizes, int n_in,
                              void* d_out, int out_size, void* d_ws, size_t ws_size,
                              hipStream_t stream) {
    const float* signal = (const float*)d_in[0];
    const void*  edges  = d_in[1];
    const float* ef     = (const float*)d_in[2];
    const float* W1 = (const float*)d_in[4];
    const float* g1 = (const float*)d_in[5];
    const float* b1 = (const float*)d_in[6];
    const float* W2 = (const float*)d_in[7];
    const float* g2 = (const float*)d_in[8];
    const float* b2 = (const float*)d_in[9];
    const float* W3 = (const float*)d_in[10];
    const float* g3 = (const float*)d_in[11];
    const float* b3 = (const float*)d_in[12];
    float* out = (float*)d_out;

    // Workspace: Y (134.2 MB) + partials (1 MB) + flag + 6x256 scale/shift
    unsigned short* Y = (unsigned short*)d_ws;
    const size_t YB = (size_t)E * COUT * sizeof(unsigned short);
    float* partials = (float*)((char*)d_ws + YB);
    char*  tail = (char*)d_ws + YB + (size_t)BLOCKS * 128 * sizeof(float);
    int*   flag = (int*)tail;
    float* ss   = (float*)(tail + 256);
    float *sc0 = ss,        *sh0 = ss + 256;
    float *sc1 = ss + 512,  *sh1 = ss + 768;
    float *sc2 = ss + 1024, *sh2 = ss + 1280;

    detect_i32<<<1, 64, 0, stream>>>((const unsigned int*)edges, flag);

    mfma_stage1<<<BLOCKS, 256, 0, stream>>>(signal, edges, ef, W1, Y, flag, partials);
    finalize_k<<<256, 256, 0, stream>>>(partials, g1, b1, sc0, sh0);

    mfma_stage<<<BLOCKS, 256, 0, stream>>>(Y, W2, sc0, sh0, partials, 1);
    finalize_k<<<256, 256, 0, stream>>>(partials, g2, b2, sc1, sh1);

    mfma_stage<<<BLOCKS, 256, 0, stream>>>(Y, W3, sc1, sh1, partials, 0);
    finalize_k<<<256, 256, 0, stream>>>(partials, g3, b3, sc2, sh2);

    pool_k<<<1024, 256, 0, stream>>>(Y, sc2, sh2, out);
}

// Round 5
// 278.123 us; speedup vs baseline: 1.1435x; 1.1435x over previous
//
#include <hip/hip_runtime.h>
#include <hip/hip_bf16.h>
#include <math.h>

// Problem constants (fixed by setup_inputs)
constexpr int B    = 4;
constexpr int N    = 8192;
constexpr int COUT = 64;
constexpr int E    = B * N * 32;      // 1048576 edges
constexpr int PERB = N * 32;          // 262144 elements per (b,o) norm group
constexpr int TILES  = E / 16;        // 65536 16-edge tiles
constexpr int TPW    = 16;            // tiles per wave (8 bn pairs)
constexpr int TPB    = TPW * 4;       // 64 tiles per block
constexpr int BLOCKS = TILES / TPB;   // 1024 (256 per batch)
constexpr float EPS   = 1e-5f;
constexpr float SLOPE = 0.1f;

// Tiled-pack activation layout (bf16):
//   addr(c, e) = (e>>4)*1024 + (c>>3)*128 + (e&15)*8 + (c&7)    [ushort units]
// -> MFMA B-frag (8 ch of one edge) = one 16B load; C-store = 8B per m-tile.

typedef __attribute__((ext_vector_type(8))) short short8;
typedef __attribute__((ext_vector_type(4))) float f32x4;
#define MFMA16 __builtin_amdgcn_mfma_f32_16x16x32_bf16

union S8 { short8 s; unsigned int u[4]; };

__device__ __forceinline__ float bflo(unsigned int u) {
    union { unsigned int x; float f; } v; v.x = u << 16; return v.f;
}
__device__ __forceinline__ float bfhi(unsigned int u) {
    union { unsigned int x; float f; } v; v.x = u & 0xFFFF0000u; return v.f;
}
// packed f32x2 -> bf16x2 (RTNE); low 16 bits = a
__device__ __forceinline__ unsigned int pk2(float a, float b) {
    union { __hip_bfloat162 h; unsigned int u; } v;
    v.h = __float22bfloat162_rn(make_float2(a, b));
    return v.u;
}
__device__ __forceinline__ float lrelu(float z) {
    return fmaxf(z, SLOPE * z);
}
__device__ __forceinline__ short8 pack8(const float* f) {
    S8 r;
#pragma unroll
    for (int i = 0; i < 4; ++i) r.u[i] = pk2(f[2 * i], f[2 * i + 1]);
    return r.s;
}
// unpack 8 bf16, apply per-channel scale/shift + leaky relu, repack bf16
__device__ __forceinline__ short8 xform(uint4 raw, const float* sc, const float* sh) {
    unsigned int w[4] = {raw.x, raw.y, raw.z, raw.w};
    S8 r;
#pragma unroll
    for (int i = 0; i < 4; ++i) {
        float z0 = fmaf(bflo(w[i]), sc[2 * i],     sh[2 * i]);
        float z1 = fmaf(bfhi(w[i]), sc[2 * i + 1], sh[2 * i + 1]);
        r.u[i] = pk2(lrelu(z0), lrelu(z1));
    }
    return r.s;
}

// ---------------------------------------------------------------------------
__global__ void detect_i32(const unsigned int* __restrict__ w, int* __restrict__ flag) {
    unsigned long long m = __ballot(w[2 * threadIdx.x + 1] != 0u);
    if (threadIdx.x == 0) *flag = (m != 0ull) ? 1 : 0;
}

// ---------------------------------------------------------------------------
// Shared epilogue: per-(b,o) sum/sumsq partials -> partials[ablk][o*2+{0,1}]
__device__ __forceinline__ void stats_epilogue(
        float (&sacc)[4][4], float (&s2acc)[4][4],
        int tid, int wv, int col, int quad, int ablk,
        float* __restrict__ partials) {
    __shared__ float lds[2][4][64];
#pragma unroll
    for (int m = 0; m < 4; ++m)
#pragma unroll
        for (int r = 0; r < 4; ++r) {
            float s = sacc[m][r], s2 = s2acc[m][r];
#pragma unroll
            for (int d = 1; d < 16; d <<= 1) {
                s  += __shfl_xor(s,  d, 16);
                s2 += __shfl_xor(s2, d, 16);
            }
            if (col == 0) {
                int o = m * 16 + quad * 4 + r;
                lds[0][wv][o] = s;
                lds[1][wv][o] = s2;
            }
        }
    __syncthreads();
    if (tid < 64) {
        float s  = lds[0][0][tid] + lds[0][1][tid] + lds[0][2][tid] + lds[0][3][tid];
        float s2 = lds[1][0][tid] + lds[1][1][tid] + lds[1][2][tid] + lds[1][3][tid];
        ((float2*)(partials + (size_t)ablk * 128))[tid] = make_float2(s, s2);
    }
}

// ---------------------------------------------------------------------------
// Layer 1: gather + concat + MFMA (K=35 padded to 64). Software-pipelined:
// edge index 2-deep, signal/ef 1-deep prefetch (clamped, always in-bounds).
__global__ __launch_bounds__(256) void mfma_stage1(
        const float* __restrict__ signal,   // (BN, 32)
        const void*  __restrict__ edges,
        const float* __restrict__ ef,       // (E, 3)
        const float* __restrict__ W1,       // (64, 35)
        unsigned short* __restrict__ Y,
        const int* __restrict__ flag,
        float* __restrict__ partials) {
    const int tid = threadIdx.x, lane = tid & 63, wv = tid >> 6;
    const int col = lane & 15, quad = lane >> 4;

    short8 afrag[4][2];
#pragma unroll
    for (int m = 0; m < 4; ++m) {
        const float* wr = W1 + (m * 16 + col) * 35;
        float f[8];
#pragma unroll
        for (int j = 0; j < 8; ++j) f[j] = wr[quad * 8 + j];
        afrag[m][0] = pack8(f);
#pragma unroll
        for (int j = 0; j < 8; ++j) f[j] = (quad == 0 && j < 3) ? wr[32 + j] : 0.f;
        afrag[m][1] = pack8(f);
    }
    const bool is32 = (*flag != 0);
    const int* ip = (const int*)edges;
    const long long* lp = (const long long*)edges;

    float sacc[4][4] = {{0.f}}, s2acc[4][4] = {{0.f}};
    const int tile0 = blockIdx.x * TPB + wv * TPW;
    const int eW = tile0 * 16 + col;      // this lane's edge for tile ti: eW + 16*ti

    // pipeline preload
    long long idxA = is32 ? (long long)ip[eW] : lp[eW];
    long long idxB = is32 ? (long long)ip[min(eW + 16, E - 1)] : lp[min(eW + 16, E - 1)];
    const float* spA = signal + idxA * 32 + quad * 8;
    float4 sA0 = *(const float4*)spA;
    float4 sA1 = *(const float4*)(spA + 4);
    float efA0 = 0.f, efA1 = 0.f, efA2 = 0.f;
    if (quad == 0) {
        const float* p = ef + (size_t)eW * 3;
        efA0 = p[0]; efA1 = p[1]; efA2 = p[2];
    }

    for (int ti = 0; ti < TPW; ++ti) {
        const int eCur = eW + ti * 16;
        // prefetch idx two ahead, signal/ef one ahead
        const int eI = min(eCur + 32, E - 1);
        long long idxC = is32 ? (long long)ip[eI] : lp[eI];
        const float* spB = signal + idxB * 32 + quad * 8;
        float4 sB0 = *(const float4*)spB;
        float4 sB1 = *(const float4*)(spB + 4);
        float efB0 = 0.f, efB1 = 0.f, efB2 = 0.f;
        if (quad == 0) {
            const float* p = ef + (size_t)min(eCur + 16, E - 1) * 3;
            efB0 = p[0]; efB1 = p[1]; efB2 = p[2];
        }
        // compute current tile from A-buffers
        float f[8] = {sA0.x, sA0.y, sA0.z, sA0.w, sA1.x, sA1.y, sA1.z, sA1.w};
        short8 b0 = pack8(f);
        float g[8] = {efA0, efA1, efA2, 0.f, 0.f, 0.f, 0.f, 0.f};
        short8 b1 = pack8(g);

        unsigned short* tp = Y + (size_t)(tile0 + ti) * 1024;
#pragma unroll
        for (int m = 0; m < 4; ++m) {
            f32x4 acc = {0.f, 0.f, 0.f, 0.f};
            acc = MFMA16(afrag[m][0], b0, acc, 0, 0, 0);
            acc = MFMA16(afrag[m][1], b1, acc, 0, 0, 0);
            *(uint2*)(tp + (m * 2 + (quad >> 1)) * 128 + col * 8 + (quad & 1) * 4) =
                make_uint2(pk2(acc[0], acc[1]), pk2(acc[2], acc[3]));
#pragma unroll
            for (int r = 0; r < 4; ++r) {
                float v = acc[r];
                sacc[m][r] += v;
                s2acc[m][r] = fmaf(v, v, s2acc[m][r]);
            }
        }
        // rotate pipeline
        sA0 = sB0; sA1 = sB1;
        efA0 = efB0; efA1 = efB1; efA2 = efB2;
        idxB = idxC;
    }
    stats_epilogue(sacc, s2acc, tid, wv, col, quad, blockIdx.x, partials);
}

// ---------------------------------------------------------------------------
// Layer 2: in-place TP GEMM: Y[o] = W * lrelu(scale*Y + shift), + stats.
// dir=1 walks blocks in reverse (LLC serpentine). One-tile-deep prefetch.
__global__ __launch_bounds__(256) void mfma_stage(
        unsigned short* __restrict__ Y,         // in-place (per-tile wave-exclusive)
        const float* __restrict__ W,            // (64, 64)
        const float* __restrict__ scale,        // (B, 64)
        const float* __restrict__ shift,
        float* __restrict__ partials,
        const int dir) {
    const int tid = threadIdx.x, lane = tid & 63, wv = tid >> 6;
    const int col = lane & 15, quad = lane >> 4;
    const int ablk = dir ? (BLOCKS - 1 - blockIdx.x) : blockIdx.x;
    const int b    = ablk >> 8;                 // 256 blocks per batch

    short8 afrag[4][2];
#pragma unroll
    for (int m = 0; m < 4; ++m)
#pragma unroll
        for (int kc = 0; kc < 2; ++kc) {
            const float4* wp = (const float4*)(W + (m * 16 + col) * 64 + kc * 32 + quad * 8);
            float4 w0 = wp[0], w1 = wp[1];
            float f[8] = {w0.x, w0.y, w0.z, w0.w, w1.x, w1.y, w1.z, w1.w};
            afrag[m][kc] = pack8(f);
        }
    float sc[2][8], sh[2][8];
#pragma unroll
    for (int kc = 0; kc < 2; ++kc) {
        const int c0 = (kc * 4 + quad) * 8;
#pragma unroll
        for (int j = 0; j < 8; ++j) {
            sc[kc][j] = scale[b * COUT + c0 + j];
            sh[kc][j] = shift[b * COUT + c0 + j];
        }
    }
    float sacc[4][4] = {{0.f}}, s2acc[4][4] = {{0.f}};
    const int tile0 = ablk * TPB + wv * TPW;
    const int off0 = quad * 128 + col * 8;

    // pipeline preload
    const unsigned short* tpA = Y + (size_t)tile0 * 1024;
    uint4 pA0 = *(const uint4*)(tpA + off0);
    uint4 pA1 = *(const uint4*)(tpA + 512 + off0);

    for (int ti = 0; ti < TPW; ++ti) {
        // prefetch next tile (clamped: last iter re-reads own last tile, discarded)
        const unsigned short* tpB = Y + (size_t)(tile0 + min(ti + 1, TPW - 1)) * 1024;
        uint4 pB0 = *(const uint4*)(tpB + off0);
        uint4 pB1 = *(const uint4*)(tpB + 512 + off0);

        short8 b0 = xform(pA0, sc[0], sh[0]);
        short8 b1 = xform(pA1, sc[1], sh[1]);
        unsigned short* tp = Y + (size_t)(tile0 + ti) * 1024;
#pragma unroll
        for (int m = 0; m < 4; ++m) {
            f32x4 acc = {0.f, 0.f, 0.f, 0.f};
            acc = MFMA16(afrag[m][0], b0, acc, 0, 0, 0);
            acc = MFMA16(afrag[m][1], b1, acc, 0, 0, 0);
            *(uint2*)(tp + (m * 2 + (quad >> 1)) * 128 + col * 8 + (quad & 1) * 4) =
                make_uint2(pk2(acc[0], acc[1]), pk2(acc[2], acc[3]));
#pragma unroll
            for (int r = 0; r < 4; ++r) {
                float v = acc[r];
                sacc[m][r] += v;
                s2acc[m][r] = fmaf(v, v, s2acc[m][r]);
            }
        }
        pA0 = pB0; pA1 = pB1;
    }
    stats_epilogue(sacc, s2acc, tid, wv, col, quad, ablk, partials);
}

// ---------------------------------------------------------------------------
// Layer 3 (last): same GEMM but does NOT write Y. Instead, per (bn, o) it
// tracks fp32 max/min of pre-norm y3 over the 32 edges (2 tiles) and writes a
// compact R record (32 bn x [64 mx | 64 mn] floats = 16 KB/block) into the
// block's own (already consumed) Y region. Stats epilogue unchanged.
__global__ __launch_bounds__(256) void mfma_stage_last(
        unsigned short* __restrict__ Y,
        const float* __restrict__ W,
        const float* __restrict__ scale,
        const float* __restrict__ shift,
        float* __restrict__ partials) {
    const int tid = threadIdx.x, lane = tid & 63, wv = tid >> 6;
    const int col = lane & 15, quad = lane >> 4;
    const int ablk = blockIdx.x;               // forward (serpentine vs stage2)
    const int b    = ablk >> 8;

    short8 afrag[4][2];
#pragma unroll
    for (int m = 0; m < 4; ++m)
#pragma unroll
        for (int kc = 0; kc < 2; ++kc) {
            const float4* wp = (const float4*)(W + (m * 16 + col) * 64 + kc * 32 + quad * 8);
            float4 w0 = wp[0], w1 = wp[1];
            float f[8] = {w0.x, w0.y, w0.z, w0.w, w1.x, w1.y, w1.z, w1.w};
            afrag[m][kc] = pack8(f);
        }
    float sc[2][8], sh[2][8];
#pragma unroll
    for (int kc = 0; kc < 2; ++kc) {
        const int c0 = (kc * 4 + quad) * 8;
#pragma unroll
        for (int j = 0; j < 8; ++j) {
            sc[kc][j] = scale[b * COUT + c0 + j];
            sh[kc][j] = shift[b * COUT + c0 + j];
        }
    }
    float sacc[4][4] = {{0.f}}, s2acc[4][4] = {{0.f}};
    const int tile0 = ablk * TPB + wv * TPW;
    const int off0 = quad * 128 + col * 8;

    __shared__ float ldsR[32][128];            // [bnloc][mx 0..63 | mn 64..127]

    const unsigned short* tpA = Y + (size_t)tile0 * 1024;
    uint4 pA0 = *(const uint4*)(tpA + off0);
    uint4 pA1 = *(const uint4*)(tpA + 512 + off0);

    for (int pr = 0; pr < TPW / 2; ++pr) {
        float mx[4][4], mn[4][4];
#pragma unroll
        for (int m = 0; m < 4; ++m)
#pragma unroll
            for (int r = 0; r < 4; ++r) { mx[m][r] = -1e30f; mn[m][r] = 1e30f; }

#pragma unroll
        for (int hf = 0; hf < 2; ++hf) {
            const int ti = pr * 2 + hf;
            const unsigned short* tpB = Y + (size_t)(tile0 + min(ti + 1, TPW - 1)) * 1024;
            uint4 pB0 = *(const uint4*)(tpB + off0);
            uint4 pB1 = *(const uint4*)(tpB + 512 + off0);

            short8 b0 = xform(pA0, sc[0], sh[0]);
            short8 b1 = xform(pA1, sc[1], sh[1]);
#pragma unroll
            for (int m = 0; m < 4; ++m) {
                f32x4 acc = {0.f, 0.f, 0.f, 0.f};
                acc = MFMA16(afrag[m][0], b0, acc, 0, 0, 0);
                acc = MFMA16(afrag[m][1], b1, acc, 0, 0, 0);
#pragma unroll
                for (int r = 0; r < 4; ++r) {
                    float v = acc[r];
                    sacc[m][r] += v;
                    s2acc[m][r] = fmaf(v, v, s2acc[m][r]);
                    mx[m][r] = fmaxf(mx[m][r], v);
                    mn[m][r] = fminf(mn[m][r], v);
                }
            }
            pA0 = pB0; pA1 = pB1;
        }
        // reduce over the 16 edge-columns (butterfly within 16-lane groups)
#pragma unroll
        for (int m = 0; m < 4; ++m)
#pragma unroll
            for (int r = 0; r < 4; ++r) {
                float x = mx[m][r], n = mn[m][r];
#pragma unroll
                for (int d = 1; d < 16; d <<= 1) {
                    x = fmaxf(x, __shfl_xor(x, d, 16));
                    n = fminf(n, __shfl_xor(n, d, 16));
                }
                if (col == 0) {
                    const int o = m * 16 + quad * 4 + r;
                    ldsR[wv * 8 + pr][o]      = x;
                    ldsR[wv * 8 + pr][64 + o] = n;
                }
            }
    }
    stats_epilogue(sacc, s2acc, tid, wv, col, quad, ablk, partials);
    // after epilogue's __syncthreads: all tile reads done, ldsR complete ->
    // safe to overwrite this block's own Y region with the compact R record.
    float4* dst = (float4*)(Y + (size_t)ablk * (TPB * 1024));
    const float4* src = (const float4*)&ldsR[0][0];
#pragma unroll
    for (int j = 0; j < 4; ++j) dst[tid + j * 256] = src[tid + j * 256];
}

// ---------------------------------------------------------------------------
// Parallel finalize: one block per (o,b); 256 threads sum that batch's partials.
__global__ __launch_bounds__(256) void finalize_k(
        const float* __restrict__ partials,
        const float* __restrict__ gamma,
        const float* __restrict__ beta,
        float* __restrict__ scale,
        float* __restrict__ shift) {
    const int g = blockIdx.x;        // 0..255
    const int o = g >> 2, b = g & 3;
    const int k = threadIdx.x;       // 0..255
    const float* p = partials + (size_t)(b * 256 + k) * 128 + o * 2;
    float s = p[0], s2 = p[1];
    __shared__ float red[512];
    red[k] = s; red[256 + k] = s2;
    __syncthreads();
    for (int st = 128; st > 0; st >>= 1) {
        if (k < st) { red[k] += red[k + st]; red[256 + k] += red[256 + k + st]; }
        __syncthreads();
    }
    if (k == 0) {
        const float inv_n = 1.f / (float)PERB;
        float mean = red[0] * inv_n;
        float var  = red[256] * inv_n - mean * mean;
        float inv  = rsqrtf(var + EPS);
        float scv  = gamma[o] * inv;
        scale[b * COUT + o] = scv;
        shift[b * COUT + o] = beta[o] - mean * scv;
    }
}

// ---------------------------------------------------------------------------
// Final pool: read compact R records (fp32 max/min of pre-norm y3), apply
// affine norm (sign-aware), one lrelu, write out[(bn)*64 + o].
__global__ __launch_bounds__(256) void pool_final(
        const unsigned short* __restrict__ Y,
        const float* __restrict__ scale,
        const float* __restrict__ shift,
        float* __restrict__ out) {
    const int t  = blockIdx.x * 256 + threadIdx.x;   // 0..262143
    const int og = t & 7;
    const int bn = t >> 3;
    const int b  = bn >> 13;
    const float* base = (const float*)(Y + (size_t)(bn >> 5) * (TPB * 1024))
                        + (bn & 31) * 128 + og * 8;
    float4 x0 = *(const float4*)(base);
    float4 x1 = *(const float4*)(base + 4);
    float4 n0 = *(const float4*)(base + 64);
    float4 n1 = *(const float4*)(base + 68);
    float mxv[8] = {x0.x, x0.y, x0.z, x0.w, x1.x, x1.y, x1.z, x1.w};
    float mnv[8] = {n0.x, n0.y, n0.z, n0.w, n1.x, n1.y, n1.z, n1.w};
    float r[8];
#pragma unroll
    for (int j = 0; j < 8; ++j) {
        const int o = og * 8 + j;
        const float s = scale[b * COUT + o], h = shift[b * COUT + o];
        float m = (s >= 0.f ? mxv[j] : mnv[j]) * s + h;
        r[j] = lrelu(m);
    }
    float4* q = (float4*)(out + (size_t)bn * COUT + og * 8);
    q[0] = make_float4(r[0], r[1], r[2], r[3]);
    q[1] = make_float4(r[4], r[5], r[6], r[7]);
}

// ---------------------------------------------------------------------------
extern "C" void kernel_launch(void* const* d_in, const int* in_sizes, int n_in,
                              void* d_out, int out_size, void* d_ws, size_t ws_size,
                              hipStream_t stream) {
    const float* signal = (const float*)d_in[0];
    const void*  edges  = d_in[1];
    const float* ef     = (const float*)d_in[2];
    const float* W1 = (const float*)d_in[4];
    const float* g1 = (const float*)d_in[5];
    const float* b1 = (const float*)d_in[6];
    const float* W2 = (const float*)d_in[7];
    const float* g2 = (const float*)d_in[8];
    const float* b2 = (const float*)d_in[9];
    const float* W3 = (const float*)d_in[10];
    const float* g3 = (const float*)d_in[11];
    const float* b3 = (const float*)d_in[12];
    float* out = (float*)d_out;

    // Workspace: Y (134.2 MB) + partials (512 KB) + flag + 6x256 scale/shift
    unsigned short* Y = (unsigned short*)d_ws;
    const size_t YB = (size_t)E * COUT * sizeof(unsigned short);
    float* partials = (float*)((char*)d_ws + YB);
    char*  tail = (char*)d_ws + YB + (size_t)BLOCKS * 128 * sizeof(float);
    int*   flag = (int*)tail;
    float* ss   = (float*)(tail + 256);
    float *sc0 = ss,        *sh0 = ss + 256;
    float *sc1 = ss + 512,  *sh1 = ss + 768;
    float *sc2 = ss + 1024, *sh2 = ss + 1280;

    detect_i32<<<1, 64, 0, stream>>>((const unsigned int*)edges, flag);

    mfma_stage1<<<BLOCKS, 256, 0, stream>>>(signal, edges, ef, W1, Y, flag, partials);
    finalize_k<<<256, 256, 0, stream>>>(partials, g1, b1, sc0, sh0);

    mfma_stage<<<BLOCKS, 256, 0, stream>>>(Y, W2, sc0, sh0, partials, 1);
    finalize_k<<<256, 256, 0, stream>>>(partials, g2, b2, sc1, sh1);

    mfma_stage_last<<<BLOCKS, 256, 0, stream>>>(Y, W3, sc1, sh1, partials);
    finalize_k<<<256, 256, 0, stream>>>(partials, g3, b3, sc2, sh2);

    pool_final<<<1024, 256, 0, stream>>>(Y, sc2, sh2, out);
}

// Round 6
// 236.761 us; speedup vs baseline: 1.3433x; 1.1747x over previous
//
#include <hip/hip_runtime.h>
#include <hip/hip_bf16.h>
#include <math.h>

// Problem constants (fixed by setup_inputs)
constexpr int B    = 4;
constexpr int N    = 8192;
constexpr int COUT = 64;
constexpr int E    = B * N * 32;      // 1048576 edges
constexpr int PERB = N * 32;          // 262144 elements per (b,o) norm group
constexpr int TILES  = E / 16;        // 65536 16-edge tiles
constexpr int TPW    = 16;            // tiles per wave (8 bn pairs)
constexpr int TPB    = TPW * 4;       // 64 tiles per block
constexpr int BLOCKS = TILES / TPB;   // 1024 (256 per batch)
constexpr float EPS   = 1e-5f;
constexpr float SLOPE = 0.1f;

// Tiled-pack activation layout (bf16):
//   addr(c, e) = (e>>4)*1024 + (c>>3)*128 + (e&15)*8 + (c&7)    [ushort units]
// -> MFMA B-frag (8 ch of one edge) = one 16B load; C-store = 8B per m-tile.

typedef __attribute__((ext_vector_type(8))) short short8;
typedef __attribute__((ext_vector_type(4))) float f32x4;
#define MFMA16 __builtin_amdgcn_mfma_f32_16x16x32_bf16

union S8 { short8 s; unsigned int u[4]; };

__device__ __forceinline__ float bflo(unsigned int u) {
    union { unsigned int x; float f; } v; v.x = u << 16; return v.f;
}
__device__ __forceinline__ float bfhi(unsigned int u) {
    union { unsigned int x; float f; } v; v.x = u & 0xFFFF0000u; return v.f;
}
// packed f32x2 -> bf16x2 (RTNE); low 16 bits = a
__device__ __forceinline__ unsigned int pk2(float a, float b) {
    union { __hip_bfloat162 h; unsigned int u; } v;
    v.h = __float22bfloat162_rn(make_float2(a, b));
    return v.u;
}
__device__ __forceinline__ float lrelu(float z) {
    return fmaxf(z, SLOPE * z);
}
__device__ __forceinline__ short8 pack8(const float* f) {
    S8 r;
#pragma unroll
    for (int i = 0; i < 4; ++i) r.u[i] = pk2(f[2 * i], f[2 * i + 1]);
    return r.s;
}
// unpack 8 bf16, apply per-channel scale/shift + leaky relu, repack bf16
__device__ __forceinline__ short8 xform(uint4 raw, const float* sc, const float* sh) {
    unsigned int w[4] = {raw.x, raw.y, raw.z, raw.w};
    S8 r;
#pragma unroll
    for (int i = 0; i < 4; ++i) {
        float z0 = fmaf(bflo(w[i]), sc[2 * i],     sh[2 * i]);
        float z1 = fmaf(bfhi(w[i]), sc[2 * i + 1], sh[2 * i + 1]);
        r.u[i] = pk2(lrelu(z0), lrelu(z1));
    }
    return r.s;
}

// ---------------------------------------------------------------------------
__global__ void detect_i32(const unsigned int* __restrict__ w, int* __restrict__ flag) {
    unsigned long long m = __ballot(w[2 * threadIdx.x + 1] != 0u);
    if (threadIdx.x == 0) *flag = (m != 0ull) ? 1 : 0;
}

// ---------------------------------------------------------------------------
// Shared epilogue: per-(b,o) sum/sumsq partials -> partials[ablk][o*2+{0,1}]
__device__ __forceinline__ void stats_epilogue(
        float (&sacc)[4][4], float (&s2acc)[4][4],
        int tid, int wv, int col, int quad, int ablk,
        float* __restrict__ partials) {
    __shared__ float lds[2][4][64];
#pragma unroll
    for (int m = 0; m < 4; ++m)
#pragma unroll
        for (int r = 0; r < 4; ++r) {
            float s = sacc[m][r], s2 = s2acc[m][r];
#pragma unroll
            for (int d = 1; d < 16; d <<= 1) {
                s  += __shfl_xor(s,  d, 16);
                s2 += __shfl_xor(s2, d, 16);
            }
            if (col == 0) {
                int o = m * 16 + quad * 4 + r;
                lds[0][wv][o] = s;
                lds[1][wv][o] = s2;
            }
        }
    __syncthreads();
    if (tid < 64) {
        float s  = lds[0][0][tid] + lds[0][1][tid] + lds[0][2][tid] + lds[0][3][tid];
        float s2 = lds[1][0][tid] + lds[1][1][tid] + lds[1][2][tid] + lds[1][3][tid];
        ((float2*)(partials + (size_t)ablk * 128))[tid] = make_float2(s, s2);
    }
}

// ---------------------------------------------------------------------------
// Layer 1: gather + concat + MFMA (K=35 padded to 64). Software-pipelined:
// edge index 2-deep, signal/ef 1-deep prefetch (clamped, always in-bounds).
__global__ __launch_bounds__(256) void mfma_stage1(
        const float* __restrict__ signal,   // (BN, 32)
        const void*  __restrict__ edges,
        const float* __restrict__ ef,       // (E, 3)
        const float* __restrict__ W1,       // (64, 35)
        unsigned short* __restrict__ Y,
        const int* __restrict__ flag,
        float* __restrict__ partials) {
    const int tid = threadIdx.x, lane = tid & 63, wv = tid >> 6;
    const int col = lane & 15, quad = lane >> 4;

    short8 afrag[4][2];
#pragma unroll
    for (int m = 0; m < 4; ++m) {
        const float* wr = W1 + (m * 16 + col) * 35;
        float f[8];
#pragma unroll
        for (int j = 0; j < 8; ++j) f[j] = wr[quad * 8 + j];
        afrag[m][0] = pack8(f);
#pragma unroll
        for (int j = 0; j < 8; ++j) f[j] = (quad == 0 && j < 3) ? wr[32 + j] : 0.f;
        afrag[m][1] = pack8(f);
    }
    const bool is32 = (*flag != 0);
    const int* ip = (const int*)edges;
    const long long* lp = (const long long*)edges;

    float sacc[4][4] = {{0.f}}, s2acc[4][4] = {{0.f}};
    const int tile0 = blockIdx.x * TPB + wv * TPW;
    const int eW = tile0 * 16 + col;      // this lane's edge for tile ti: eW + 16*ti

    // pipeline preload
    long long idxA = is32 ? (long long)ip[eW] : lp[eW];
    long long idxB = is32 ? (long long)ip[min(eW + 16, E - 1)] : lp[min(eW + 16, E - 1)];
    const float* spA = signal + idxA * 32 + quad * 8;
    float4 sA0 = *(const float4*)spA;
    float4 sA1 = *(const float4*)(spA + 4);
    float efA0 = 0.f, efA1 = 0.f, efA2 = 0.f;
    if (quad == 0) {
        const float* p = ef + (size_t)eW * 3;
        efA0 = p[0]; efA1 = p[1]; efA2 = p[2];
    }

    for (int ti = 0; ti < TPW; ++ti) {
        const int eCur = eW + ti * 16;
        // prefetch idx two ahead, signal/ef one ahead
        const int eI = min(eCur + 32, E - 1);
        long long idxC = is32 ? (long long)ip[eI] : lp[eI];
        const float* spB = signal + idxB * 32 + quad * 8;
        float4 sB0 = *(const float4*)spB;
        float4 sB1 = *(const float4*)(spB + 4);
        float efB0 = 0.f, efB1 = 0.f, efB2 = 0.f;
        if (quad == 0) {
            const float* p = ef + (size_t)min(eCur + 16, E - 1) * 3;
            efB0 = p[0]; efB1 = p[1]; efB2 = p[2];
        }
        // compute current tile from A-buffers
        float f[8] = {sA0.x, sA0.y, sA0.z, sA0.w, sA1.x, sA1.y, sA1.z, sA1.w};
        short8 b0 = pack8(f);
        float g[8] = {efA0, efA1, efA2, 0.f, 0.f, 0.f, 0.f, 0.f};
        short8 b1 = pack8(g);

        unsigned short* tp = Y + (size_t)(tile0 + ti) * 1024;
#pragma unroll
        for (int m = 0; m < 4; ++m) {
            f32x4 acc = {0.f, 0.f, 0.f, 0.f};
            acc = MFMA16(afrag[m][0], b0, acc, 0, 0, 0);
            acc = MFMA16(afrag[m][1], b1, acc, 0, 0, 0);
            *(uint2*)(tp + (m * 2 + (quad >> 1)) * 128 + col * 8 + (quad & 1) * 4) =
                make_uint2(pk2(acc[0], acc[1]), pk2(acc[2], acc[3]));
#pragma unroll
            for (int r = 0; r < 4; ++r) {
                float v = acc[r];
                sacc[m][r] += v;
                s2acc[m][r] = fmaf(v, v, s2acc[m][r]);
            }
        }
        // rotate pipeline
        sA0 = sB0; sA1 = sB1;
        efA0 = efB0; efA1 = efB1; efA2 = efB2;
        idxB = idxC;
    }
    stats_epilogue(sacc, s2acc, tid, wv, col, quad, blockIdx.x, partials);
}

// ---------------------------------------------------------------------------
// Layer 2: in-place TP GEMM: Y[o] = W * lrelu(scale*Y + shift), + stats.
// dir=1 walks blocks in reverse (LLC serpentine). One-tile-deep prefetch.
__global__ __launch_bounds__(256) void mfma_stage(
        unsigned short* __restrict__ Y,         // in-place (per-tile wave-exclusive)
        const float* __restrict__ W,            // (64, 64)
        const float* __restrict__ scale,        // (B, 64)
        const float* __restrict__ shift,
        float* __restrict__ partials,
        const int dir) {
    const int tid = threadIdx.x, lane = tid & 63, wv = tid >> 6;
    const int col = lane & 15, quad = lane >> 4;
    const int ablk = dir ? (BLOCKS - 1 - blockIdx.x) : blockIdx.x;
    const int b    = ablk >> 8;                 // 256 blocks per batch

    short8 afrag[4][2];
#pragma unroll
    for (int m = 0; m < 4; ++m)
#pragma unroll
        for (int kc = 0; kc < 2; ++kc) {
            const float4* wp = (const float4*)(W + (m * 16 + col) * 64 + kc * 32 + quad * 8);
            float4 w0 = wp[0], w1 = wp[1];
            float f[8] = {w0.x, w0.y, w0.z, w0.w, w1.x, w1.y, w1.z, w1.w};
            afrag[m][kc] = pack8(f);
        }
    float sc[2][8], sh[2][8];
#pragma unroll
    for (int kc = 0; kc < 2; ++kc) {
        const int c0 = (kc * 4 + quad) * 8;
#pragma unroll
        for (int j = 0; j < 8; ++j) {
            sc[kc][j] = scale[b * COUT + c0 + j];
            sh[kc][j] = shift[b * COUT + c0 + j];
        }
    }
    float sacc[4][4] = {{0.f}}, s2acc[4][4] = {{0.f}};
    const int tile0 = ablk * TPB + wv * TPW;
    const int off0 = quad * 128 + col * 8;

    // pipeline preload
    const unsigned short* tpA = Y + (size_t)tile0 * 1024;
    uint4 pA0 = *(const uint4*)(tpA + off0);
    uint4 pA1 = *(const uint4*)(tpA + 512 + off0);

    for (int ti = 0; ti < TPW; ++ti) {
        // prefetch next tile (clamped: last iter re-reads own last tile, discarded)
        const unsigned short* tpB = Y + (size_t)(tile0 + min(ti + 1, TPW - 1)) * 1024;
        uint4 pB0 = *(const uint4*)(tpB + off0);
        uint4 pB1 = *(const uint4*)(tpB + 512 + off0);

        short8 b0 = xform(pA0, sc[0], sh[0]);
        short8 b1 = xform(pA1, sc[1], sh[1]);
        unsigned short* tp = Y + (size_t)(tile0 + ti) * 1024;
#pragma unroll
        for (int m = 0; m < 4; ++m) {
            f32x4 acc = {0.f, 0.f, 0.f, 0.f};
            acc = MFMA16(afrag[m][0], b0, acc, 0, 0, 0);
            acc = MFMA16(afrag[m][1], b1, acc, 0, 0, 0);
            *(uint2*)(tp + (m * 2 + (quad >> 1)) * 128 + col * 8 + (quad & 1) * 4) =
                make_uint2(pk2(acc[0], acc[1]), pk2(acc[2], acc[3]));
#pragma unroll
            for (int r = 0; r < 4; ++r) {
                float v = acc[r];
                sacc[m][r] += v;
                s2acc[m][r] = fmaf(v, v, s2acc[m][r]);
            }
        }
        pA0 = pB0; pA1 = pB1;
    }
    stats_epilogue(sacc, s2acc, tid, wv, col, quad, ablk, partials);
}

// ---------------------------------------------------------------------------
// Layer 3 (last): GEMM without Y writeback. Per bn pair (2 tiles) tracks fp32
// max/min of pre-norm y3; per-lane values go through a WAVE-PRIVATE col-swizzled
// LDS slice (no cross-wave traffic -> no barriers), each lane then owns one
// output channel and writes the compact R record (64 mx + 64 mn floats) into
// the wave's OWN just-consumed tile 2*pr region. Race-free by program order.
__global__ __launch_bounds__(256) void mfma_stage_last(
        unsigned short* __restrict__ Y,
        const float* __restrict__ W,
        const float* __restrict__ scale,
        const float* __restrict__ shift,
        float* __restrict__ partials) {
    const int tid = threadIdx.x, lane = tid & 63, wv = tid >> 6;
    const int col = lane & 15, quad = lane >> 4;
    const int ablk = blockIdx.x;
    const int b    = ablk >> 8;

    short8 afrag[4][2];
#pragma unroll
    for (int m = 0; m < 4; ++m)
#pragma unroll
        for (int kc = 0; kc < 2; ++kc) {
            const float4* wp = (const float4*)(W + (m * 16 + col) * 64 + kc * 32 + quad * 8);
            float4 w0 = wp[0], w1 = wp[1];
            float f[8] = {w0.x, w0.y, w0.z, w0.w, w1.x, w1.y, w1.z, w1.w};
            afrag[m][kc] = pack8(f);
        }
    float sc[2][8], sh[2][8];
#pragma unroll
    for (int kc = 0; kc < 2; ++kc) {
        const int c0 = (kc * 4 + quad) * 8;
#pragma unroll
        for (int j = 0; j < 8; ++j) {
            sc[kc][j] = scale[b * COUT + c0 + j];
            sh[kc][j] = shift[b * COUT + c0 + j];
        }
    }
    float sacc[4][4] = {{0.f}}, s2acc[4][4] = {{0.f}};
    const int tile0 = ablk * TPB + wv * TPW;
    const int off0 = quad * 128 + col * 8;

    // wave-private slices: [wv][col(16)][o(64) x (mx,mn)] fp32, col-swizzled
    __shared__ float ldsP[4][2048];              // 32 KB
    float* P = ldsP[wv];
    const int swz = (col & 7) << 2;

    const unsigned short* tpA = Y + (size_t)tile0 * 1024;
    uint4 pA0 = *(const uint4*)(tpA + off0);
    uint4 pA1 = *(const uint4*)(tpA + 512 + off0);

    for (int pr = 0; pr < TPW / 2; ++pr) {
        float mx[4][4], mn[4][4];
#pragma unroll
        for (int m = 0; m < 4; ++m)
#pragma unroll
            for (int r = 0; r < 4; ++r) { mx[m][r] = -1e30f; mn[m][r] = 1e30f; }

#pragma unroll
        for (int hf = 0; hf < 2; ++hf) {
            const int ti = pr * 2 + hf;
            const unsigned short* tpB = Y + (size_t)(tile0 + min(ti + 1, TPW - 1)) * 1024;
            uint4 pB0 = *(const uint4*)(tpB + off0);
            uint4 pB1 = *(const uint4*)(tpB + 512 + off0);

            short8 b0 = xform(pA0, sc[0], sh[0]);
            short8 b1 = xform(pA1, sc[1], sh[1]);
#pragma unroll
            for (int m = 0; m < 4; ++m) {
                f32x4 acc = {0.f, 0.f, 0.f, 0.f};
                acc = MFMA16(afrag[m][0], b0, acc, 0, 0, 0);
                acc = MFMA16(afrag[m][1], b1, acc, 0, 0, 0);
#pragma unroll
                for (int r = 0; r < 4; ++r) {
                    float v = acc[r];
                    sacc[m][r] += v;
                    s2acc[m][r] = fmaf(v, v, s2acc[m][r]);
                    mx[m][r] = fmaxf(mx[m][r], v);
                    mn[m][r] = fminf(mn[m][r], v);
                }
            }
            pA0 = pB0; pA1 = pB1;
        }
        // stash per-lane (mx,mn) into the wave slice (8x ds_write_b128, 2-way max)
#pragma unroll
        for (int m = 0; m < 4; ++m) {
            const int fi0 = col * 128 + m * 32 + quad * 8;
            float4 lo = {mx[m][0], mn[m][0], mx[m][1], mn[m][1]};
            float4 hi = {mx[m][2], mn[m][2], mx[m][3], mn[m][3]};
            *(float4*)&P[fi0 ^ swz] = lo;
            *(float4*)&P[(fi0 + 4) ^ swz] = hi;
        }
        __builtin_amdgcn_wave_barrier();
        // wave-local reduce over the 16 edge-columns: lane owns channel o=lane
        float gx = -1e30f, gn = 1e30f;
#pragma unroll
        for (int cc = 0; cc < 16; ++cc) {
            const float2 v = *(const float2*)&P[(cc * 128 + lane * 2) ^ ((cc & 7) << 2)];
            gx = fmaxf(gx, v.x);
            gn = fminf(gn, v.y);
        }
        __builtin_amdgcn_wave_barrier();
        // compact R record into this wave's OWN already-read tile 2*pr region
        float* R = (float*)(Y + (size_t)(tile0 + 2 * pr) * 1024);
        R[lane]      = gx;
        R[64 + lane] = gn;
    }
    stats_epilogue(sacc, s2acc, tid, wv, col, quad, ablk, partials);
}

// ---------------------------------------------------------------------------
// Parallel finalize: one block per (o,b); 256 threads sum that batch's partials.
__global__ __launch_bounds__(256) void finalize_k(
        const float* __restrict__ partials,
        const float* __restrict__ gamma,
        const float* __restrict__ beta,
        float* __restrict__ scale,
        float* __restrict__ shift) {
    const int g = blockIdx.x;        // 0..255
    const int o = g >> 2, b = g & 3;
    const int k = threadIdx.x;       // 0..255
    const float* p = partials + (size_t)(b * 256 + k) * 128 + o * 2;
    float s = p[0], s2 = p[1];
    __shared__ float red[512];
    red[k] = s; red[256 + k] = s2;
    __syncthreads();
    for (int st = 128; st > 0; st >>= 1) {
        if (k < st) { red[k] += red[k + st]; red[256 + k] += red[256 + k + st]; }
        __syncthreads();
    }
    if (k == 0) {
        const float inv_n = 1.f / (float)PERB;
        float mean = red[0] * inv_n;
        float var  = red[256] * inv_n - mean * mean;
        float inv  = rsqrtf(var + EPS);
        float scv  = gamma[o] * inv;
        scale[b * COUT + o] = scv;
        shift[b * COUT + o] = beta[o] - mean * scv;
    }
}

// ---------------------------------------------------------------------------
// Final pool: read compact R records (fp32 max/min of pre-norm y3) from the
// per-(wv,pr) slots inside Y, apply affine norm (sign-aware), one lrelu.
__global__ __launch_bounds__(256) void pool_final(
        const unsigned short* __restrict__ Y,
        const float* __restrict__ scale,
        const float* __restrict__ shift,
        float* __restrict__ out) {
    const int t  = blockIdx.x * 256 + threadIdx.x;   // 0..262143
    const int og = t & 7;
    const int bn = t >> 3;
    const int b  = bn >> 13;
    const int ablk = bn >> 5;
    const int wv   = (bn >> 3) & 3;
    const int pr   = bn & 7;
    const float* base =
        (const float*)(Y + (size_t)(ablk * TPB + wv * TPW + 2 * pr) * 1024);
    float4 x0 = *(const float4*)(base + og * 8);
    float4 x1 = *(const float4*)(base + og * 8 + 4);
    float4 n0 = *(const float4*)(base + 64 + og * 8);
    float4 n1 = *(const float4*)(base + 68 + og * 8);
    float mxv[8] = {x0.x, x0.y, x0.z, x0.w, x1.x, x1.y, x1.z, x1.w};
    float mnv[8] = {n0.x, n0.y, n0.z, n0.w, n1.x, n1.y, n1.z, n1.w};
    float r[8];
#pragma unroll
    for (int j = 0; j < 8; ++j) {
        const int o = og * 8 + j;
        const float s = scale[b * COUT + o], h = shift[b * COUT + o];
        float m = (s >= 0.f ? mxv[j] : mnv[j]) * s + h;
        r[j] = lrelu(m);
    }
    float4* q = (float4*)(out + (size_t)bn * COUT + og * 8);
    q[0] = make_float4(r[0], r[1], r[2], r[3]);
    q[1] = make_float4(r[4], r[5], r[6], r[7]);
}

// ---------------------------------------------------------------------------
extern "C" void kernel_launch(void* const* d_in, const int* in_sizes, int n_in,
                              void* d_out, int out_size, void* d_ws, size_t ws_size,
                              hipStream_t stream) {
    const float* signal = (const float*)d_in[0];
    const void*  edges  = d_in[1];
    const float* ef     = (const float*)d_in[2];
    const float* W1 = (const float*)d_in[4];
    const float* g1 = (const float*)d_in[5];
    const float* b1 = (const float*)d_in[6];
    const float* W2 = (const float*)d_in[7];
    const float* g2 = (const float*)d_in[8];
    const float* b2 = (const float*)d_in[9];
    const float* W3 = (const float*)d_in[10];
    const float* g3 = (const float*)d_in[11];
    const float* b3 = (const float*)d_in[12];
    float* out = (float*)d_out;

    // Workspace: Y (134.2 MB) + partials (512 KB) + flag + 6x256 scale/shift
    unsigned short* Y = (unsigned short*)d_ws;
    const size_t YB = (size_t)E * COUT * sizeof(unsigned short);
    float* partials = (float*)((char*)d_ws + YB);
    char*  tail = (char*)d_ws + YB + (size_t)BLOCKS * 128 * sizeof(float);
    int*   flag = (int*)tail;
    float* ss   = (float*)(tail + 256);
    float *sc0 = ss,        *sh0 = ss + 256;
    float *sc1 = ss + 512,  *sh1 = ss + 768;
    float *sc2 = ss + 1024, *sh2 = ss + 1280;

    detect_i32<<<1, 64, 0, stream>>>((const unsigned int*)edges, flag);

    mfma_stage1<<<BLOCKS, 256, 0, stream>>>(signal, edges, ef, W1, Y, flag, partials);
    finalize_k<<<256, 256, 0, stream>>>(partials, g1, b1, sc0, sh0);

    mfma_stage<<<BLOCKS, 256, 0, stream>>>(Y, W2, sc0, sh0, partials, 1);
    finalize_k<<<256, 256, 0, stream>>>(partials, g2, b2, sc1, sh1);

    mfma_stage_last<<<BLOCKS, 256, 0, stream>>>(Y, W3, sc1, sh1, partials);
    finalize_k<<<256, 256, 0, stream>>>(partials, g3, b3, sc2, sh2);

    pool_final<<<1024, 256, 0, stream>>>(Y, sc2, sh2, out);
}